// Round 13
// baseline (212.726 us; speedup 1.0000x reference)
//
#include <hip/hip_runtime.h>
#include <hip/hip_bf16.h>
#include <stdint.h>

#define DEV __device__ __forceinline__

typedef short     s16x8  __attribute__((ext_vector_type(8)));
typedef __bf16    bf16v8 __attribute__((ext_vector_type(8)));
typedef float     f32x4  __attribute__((ext_vector_type(4)));
typedef float     f32x16 __attribute__((ext_vector_type(16)));
typedef unsigned int u32x2 __attribute__((ext_vector_type(2)));

// ---------- helpers ----------
DEV unsigned short f2bf(float x) {
    uint32_t u = __float_as_uint(x);
    uint32_t r = (u + 0x7FFFu + ((u >> 16) & 1u)) >> 16;
    return (unsigned short)r;
}
DEV float bf2f(uint32_t u) { return __uint_as_float(u << 16); }

DEV void gload_lds16(const void* g, void* l) {
    __builtin_amdgcn_global_load_lds((const __attribute__((address_space(1))) void*)g,
                                     (__attribute__((address_space(3))) void*)l,
                                     16, 0, 0);
}

DEV f32x4 mfma16(s16x8 a, s16x8 b, f32x4 c) {
    return __builtin_amdgcn_mfma_f32_16x16x32_bf16(
        __builtin_bit_cast(bf16v8, a), __builtin_bit_cast(bf16v8, b), c, 0, 0, 0);
}
DEV f32x16 mfma32(s16x8 a, s16x8 b, f32x16 c) {
    return __builtin_amdgcn_mfma_f32_32x32x16_bf16(
        __builtin_bit_cast(bf16v8, a), __builtin_bit_cast(bf16v8, b), c, 0, 0, 0);
}

DEV uint32_t cvtpk_bf16(float lo, float hi) {
    uint32_t r;
    asm volatile("v_cvt_pk_bf16_f32 %0, %1, %2" : "=v"(r) : "v"(lo), "v"(hi));
    return r;
}

DEV u32x2 pl32swap(uint32_t a, uint32_t b) {
    return __builtin_amdgcn_permlane32_swap(a, b, false, false);
}
DEV float cross_max(float x) {
    u32x2 r = pl32swap(__float_as_uint(x), __float_as_uint(x));
    return fmaxf(__uint_as_float(r[0]), __uint_as_float(r[1]));
}
DEV float cross_sum(float x) {
    u32x2 r = pl32swap(__float_as_uint(x), __float_as_uint(x));
    return __uint_as_float(r[0]) + __uint_as_float(r[1]);
}

DEV void barx() {
    asm volatile("" ::: "memory");
    __builtin_amdgcn_s_barrier();
    __builtin_amdgcn_sched_barrier(0);
    asm volatile("" ::: "memory");
}

// ---------- elementwise f32 -> bf16 ----------
__global__ void f32_to_bf16_k(const float* __restrict__ in, short* __restrict__ out, int n8) {
    int i = blockIdx.x * blockDim.x + threadIdx.x;
    if (i >= n8) return;
    const float4 a = *(const float4*)(in + (size_t)i * 8);
    const float4 b = *(const float4*)(in + (size_t)i * 8 + 4);
    uint4 w;
    w.x = (uint32_t)f2bf(a.x) | ((uint32_t)f2bf(a.y) << 16);
    w.y = (uint32_t)f2bf(a.z) | ((uint32_t)f2bf(a.w) << 16);
    w.z = (uint32_t)f2bf(b.x) | ((uint32_t)f2bf(b.y) << 16);
    w.w = (uint32_t)f2bf(b.z) | ((uint32_t)f2bf(b.w) << 16);
    *(uint4*)(out + (size_t)i * 8) = w;
}

// ---------- tiled transpose f32 (R x C) -> bf16 (C x R) ----------
__global__ __launch_bounds__(256) void transpose_f32_bf16_k(
    const float* __restrict__ in, size_t in_batch, int ld_in,
    short* __restrict__ out, size_t out_batch, int ld_out) {
    __shared__ float tile[64][65];
    const float* ip = in + (size_t)blockIdx.z * in_batch;
    short* op = out + (size_t)blockIdx.z * out_batch;
    const int c0 = blockIdx.x * 64, r0 = blockIdx.y * 64;
    const int t = threadIdx.x;
    const int cc4 = (t & 15) * 4;
    const int rr  = t >> 4;
#pragma unroll
    for (int p = 0; p < 4; ++p) {
        int r = rr + p * 16;
        float4 v = *(const float4*)(ip + (size_t)(r0 + r) * ld_in + c0 + cc4);
        tile[r][cc4 + 0] = v.x; tile[r][cc4 + 1] = v.y;
        tile[r][cc4 + 2] = v.z; tile[r][cc4 + 3] = v.w;
    }
    __syncthreads();
#pragma unroll
    for (int p = 0; p < 4; ++p) {
        int oc  = (t >> 4) + p * 16;
        int rr4 = (t & 15) * 4;
        ushort4 w;
        w.x = f2bf(tile[rr4 + 0][oc]);
        w.y = f2bf(tile[rr4 + 1][oc]);
        w.z = f2bf(tile[rr4 + 2][oc]);
        w.w = f2bf(tile[rr4 + 3][oc]);
        *(ushort4*)(op + (size_t)(c0 + oc) * ld_out + r0 + rr4) = w;
    }
}

// ---------- tiled transpose bf16 (R x C) -> bf16 (C x R) ----------
__global__ __launch_bounds__(256) void transpose_bf16_k(
    const short* __restrict__ in, size_t in_batch, int ld_in,
    short* __restrict__ out, size_t out_batch, int ld_out) {
    __shared__ short tile[64][72];
    const short* ip = in + (size_t)blockIdx.z * in_batch;
    short* op = out + (size_t)blockIdx.z * out_batch;
    const int c0 = blockIdx.x * 64, r0 = blockIdx.y * 64;
    const int t = threadIdx.x;
    const int cc = (t & 7) * 8;
    const int rr = t >> 3;
#pragma unroll
    for (int p = 0; p < 2; ++p) {
        int r = rr + p * 32;
        s16x8 v = *(const s16x8*)(ip + (size_t)(r0 + r) * ld_in + c0 + cc);
        *(s16x8*)&tile[r][cc] = v;
    }
    __syncthreads();
    const int oc = t >> 2;
    const int rb = (t & 3) * 16;
    s16x8 w0, w1;
#pragma unroll
    for (int j = 0; j < 8; ++j) w0[j] = tile[rb + j][oc];
#pragma unroll
    for (int j = 0; j < 8; ++j) w1[j] = tile[rb + 8 + j][oc];
    *(s16x8*)(op + (size_t)(c0 + oc) * ld_out + r0 + rb) = w0;
    *(s16x8*)(op + (size_t)(c0 + oc) * ld_out + r0 + rb + 8) = w1;
}

// ---------- bias concat ----------
__global__ void concat_bias_k(const float* __restrict__ bq, const float* __restrict__ bk,
                              const float* __restrict__ bv, float* __restrict__ o) {
    int i = blockIdx.x * 256 + threadIdx.x;
    if (i < 2048)       o[i] = bq[i];
    else if (i < 2560)  o[i] = bk[i - 2048];
    else if (i < 3072)  o[i] = bv[i - 2560];
}

// ---------- GEMM v6: 256 x (NF*64) tile, 4-phase counted-vmcnt ----------
// Phases per K-tile: P(mh,ks) = {4 A-frag + NF B-frag ds_read (one ks) ||
// stage -> setprio MFMA 4xNF -> counted wait -> barrier}.
// Issue order/tile: A0,A2 | B0..B(NF-1) | - | A1,A3.
// Ledger: end-P01 vmcnt(NF+2) -> this tile's A1,A3 landed (needed P10/P11).
//         end-P11 vmcnt(2)    -> next tile's A0,A2,B* landed (needed P00).
template<int TAG, bool OUTBF, int NF>
__global__ __launch_bounds__(512, 2) void gemm256_k(
    const short* __restrict__ A, const short* __restrict__ Bt,
    const float* __restrict__ bias, void* __restrict__ Cv,
    int M, int N, int K) {
    __shared__ short As[2][16384];
    __shared__ short Bs[2][NF * 4096];
    const int tid = threadIdx.x;
    const int gx = gridDim.x;
    const int nwg = gx * gridDim.y;
    const int flat = blockIdx.y * gx + blockIdx.x;
    const int cpx = nwg >> 3;
    const int swz = (flat & 7) * cpx + (flat >> 3);
    const int m0 = (swz / gx) * 256, n0 = (swz % gx) * (NF * 64);
    const int lane = tid & 63, wid = tid >> 6;
    const int wm = wid >> 2, wn = wid & 3;
    const int lr = lane & 15, lg = lane >> 4;

    const int srow = tid >> 3;
    const int schunk = ((tid & 7) ^ (srow & 7)) << 3;
    const short* Ag = A  + (size_t)(m0 + srow) * K + schunk;
    const short* Bg = Bt + (size_t)(n0 + srow) * K + schunk;
    const int lwb = (tid & ~63) * 8;

    f32x4 acc[8][NF];
#pragma unroll
    for (int fr = 0; fr < 8; ++fr)
#pragma unroll
        for (int fc = 0; fc < NF; ++fc)
#pragma unroll
            for (int r = 0; r < 4; ++r) acc[fr][fc][r] = 0.f;

    const int nk = K >> 6;

#define SA(u, kt, dd) gload_lds16(Ag + (size_t)(u) * 64 * K + (kt) * 64, &As[dd][(u) * 4096 + lwb])
#define SB(u, kt, dd) gload_lds16(Bg + (size_t)(u) * 64 * K + (kt) * 64, &Bs[dd][(u) * 4096 + lwb])
#define STG_A02()  do { SA(0, t + 1, e); SA(2, t + 1, e); } while (0)
#define STG_A13()  do { SA(1, t + 1, e); SA(3, t + 1, e); } while (0)
#define STG_BALL() do { _Pragma("unroll") for (int u = 0; u < NF; ++u) SB(u, t + 1, e); } while (0)
#define STG_NONE() do { } while (0)

    // prologue: tile 0 fully staged
    SA(0, 0, 0); SA(1, 0, 0); SA(2, 0, 0); SA(3, 0, 0);
#pragma unroll
    for (int u = 0; u < NF; ++u) SB(u, 0, 0);
    asm volatile("s_waitcnt vmcnt(0)" ::: "memory");
    barx();

#define PH(mh, ks, STGM, WAITM)                                                \
    {                                                                          \
        s16x8 af[4]; s16x8 bf[NF];                                             \
        const int csw = (((ks) * 4 + lg) ^ (lr & 7)) * 8;                      \
        _Pragma("unroll")                                                      \
        for (int i = 0; i < 4; ++i)                                            \
            af[i] = *(const s16x8*)&As[d][(wm * 128 + (mh) * 64 + i * 16 + lr) * 64 + csw]; \
        _Pragma("unroll")                                                      \
        for (int j = 0; j < NF; ++j)                                           \
            bf[j] = *(const s16x8*)&Bs[d][(wn * (NF * 16) + j * 16 + lr) * 64 + csw]; \
        if (more) { STGM; }                                                    \
        __builtin_amdgcn_s_setprio(1);                                         \
        _Pragma("unroll")                                                      \
        for (int i = 0; i < 4; ++i)                                            \
            _Pragma("unroll")                                                  \
            for (int j = 0; j < NF; ++j)                                       \
                acc[(mh) * 4 + i][j] = mfma16(af[i], bf[j], acc[(mh) * 4 + i][j]); \
        __builtin_amdgcn_s_setprio(0);                                         \
        WAITM;                                                                 \
        barx();                                                                \
    }

    for (int t = 0; t < nk; ++t) {
        const int d = t & 1, e = d ^ 1;
        const bool more = (t + 1 < nk);
        PH(0, 0, STG_A02(), );
        PH(0, 1, STG_BALL(),
           if (more) { asm volatile("s_waitcnt vmcnt(%0)" :: "i"(NF + 2) : "memory"); }
           else      { asm volatile("s_waitcnt vmcnt(0)" ::: "memory"); });
        PH(1, 0, STG_NONE(), );
        PH(1, 1, STG_A13(),
           if (more) { asm volatile("s_waitcnt vmcnt(2)" ::: "memory"); });
    }
#undef PH
#undef SA
#undef SB
#undef STG_A02
#undef STG_A13
#undef STG_BALL
#undef STG_NONE

    // epilogue
#pragma unroll
    for (int fr = 0; fr < 8; ++fr) {
        const int row = m0 + wm * 128 + fr * 16 + lg * 4;
#pragma unroll
        for (int fc = 0; fc < NF; ++fc) {
            const int col = n0 + wn * (NF * 16) + fc * 16 + lr;
            const float bbv = bias[col];
            if constexpr (OUTBF) {
                short* Cs = (short*)Cv;
#pragma unroll
                for (int r = 0; r < 4; ++r)
                    Cs[(size_t)(row + r) * N + col] = (short)f2bf(acc[fr][fc][r] + bbv);
            } else {
                float* Cf = (float*)Cv;
#pragma unroll
                for (int r = 0; r < 4; ++r)
                    Cf[(size_t)(row + r) * N + col] = acc[fr][fc][r] + bbv;
            }
        }
    }
}

// ---------- rmsnorm + rope + head layout for Q,K (bf16 Y input) ----------
__global__ __launch_bounds__(256) void qkv_post_k(
    const short* __restrict__ Y, const float* __restrict__ qn_w,
    const float* __restrict__ kn_w, const int* __restrict__ start_pos,
    short* __restrict__ Qb, short* __restrict__ Kb) {
    const int m = blockIdx.x;
    const int b = m >> 11, s = m & 2047;
    const short* y = Y + (size_t)m * 3072;
    const int tid = threadIdx.x;

    s16x8 qv = *(const s16x8*)(y + tid * 8);
    float qn[8];
#pragma unroll
    for (int j = 0; j < 8; ++j) qn[j] = bf2f((uint32_t)(unsigned short)qv[j]);
    const uint32_t kvu = *(const uint32_t*)(y + 2048 + tid * 2);
    float k1 = bf2f(kvu & 0xffffu), k2 = bf2f(kvu >> 16);

    float ssq = qn[0]*qn[0] + qn[1]*qn[1] + qn[2]*qn[2] + qn[3]*qn[3]
              + qn[4]*qn[4] + qn[5]*qn[5] + qn[6]*qn[6] + qn[7]*qn[7];
    float ssk = k1 * k1 + k2 * k2;
#pragma unroll
    for (int off = 1; off < 64; off <<= 1) {
        ssq += __shfl_xor(ssq, off);
        ssk += __shfl_xor(ssk, off);
    }
    __shared__ float red[8];
    if ((tid & 63) == 0) { red[tid >> 6] = ssq; red[4 + (tid >> 6)] = ssk; }
    __syncthreads();
    const float tq = red[0] + red[1] + red[2] + red[3];
    const float tk = red[4] + red[5] + red[6] + red[7];
    const float rq = rsqrtf(tq * (1.f / 2048.f) + 1.1920929e-07f);
    const float rk = rsqrtf(tk * (1.f / 512.f) + 1.1920929e-07f);
    const int pos = start_pos[0] + s;

#pragma unroll
    for (int j = 0; j < 8; ++j) qn[j] *= rq * qn_w[tid * 8 + j];
    const int hq = tid >> 4;
    const int din = (tid * 8) & 127;
    unsigned short ob[8];
#pragma unroll
    for (int j = 0; j < 4; ++j) {
        int tt = (din >> 1) + j;
        float inv = __builtin_exp2f(-0.20762050f * (float)tt);
        float ang = (float)pos * inv;
        float sn, cn;
        __sincosf(ang, &sn, &cn);
        float x1 = qn[2 * j], x2 = qn[2 * j + 1];
        ob[2 * j]     = f2bf(x1 * cn - x2 * sn);
        ob[2 * j + 1] = f2bf(x1 * sn + x2 * cn);
    }
    short* qdst = Qb + (((size_t)(b * 16 + hq) * 2048 + s) * 128 + din);
    uint4 w;
    w.x = (uint32_t)ob[0] | ((uint32_t)ob[1] << 16);
    w.y = (uint32_t)ob[2] | ((uint32_t)ob[3] << 16);
    w.z = (uint32_t)ob[4] | ((uint32_t)ob[5] << 16);
    w.w = (uint32_t)ob[6] | ((uint32_t)ob[7] << 16);
    *(uint4*)qdst = w;

    const int colk = tid * 2;
    const int hk = colk >> 7, dk = colk & 127;
    float kk1 = k1 * rk * kn_w[colk], kk2 = k2 * rk * kn_w[colk + 1];
    {
        int tt = dk >> 1;
        float inv = __builtin_exp2f(-0.20762050f * (float)tt);
        float ang = (float)pos * inv;
        float sn, cn;
        __sincosf(ang, &sn, &cn);
        float r1 = kk1 * cn - kk2 * sn, r2 = kk1 * sn + kk2 * cn;
        short* kdst = Kb + (((size_t)(b * 4 + hk) * 2048 + s) * 128 + dk);
        *(uint32_t*)kdst = (uint32_t)f2bf(r1) | ((uint32_t)f2bf(r2) << 16);
    }
}

// ---------- flash attention v7 (unchanged from r12, 84 us) ----------
__global__ __launch_bounds__(512, 1) void attn_fwd_k(
    const short* __restrict__ Qb, const short* __restrict__ Kb,
    const short* __restrict__ Vtb, const float* __restrict__ gate_logits,
    short* __restrict__ attnb) {
    const int S = 2048;
    __shared__ short KV[2][2][16384];
    const int tid = threadIdx.x, lane = tid & 63;
    const int wid = tid >> 6;
    const int g = wid >> 2;
    const int hw = wid & 3;
    const int y = blockIdx.y;
    const int bhk = blockIdx.x;
    const int b = bhk >> 2, hk = bhk & 3;
    const int h = hk * 4 + hw;
    const int qtA = 63 - y, qtB = y;
    const int nA = (qtA + 2) >> 1, nB = (qtB + 2) >> 1;
    const int ql = lane & 31, hi = lane >> 5;
    const float cs = 0.12751745f;
    const float THR = 90.509668f;
    const float gl = gate_logits[h];
    const float gate = 1.f / (1.f + __expf(-gl));

    int q0 = (g == 0 ? qtA : qtB) * 32;
    int qg = q0 + ql;

    s16x8 qf[8];
#pragma unroll
    for (int kc = 0; kc < 8; ++kc)
        qf[kc] = *(const s16x8*)(Qb + (((size_t)(b * 16 + h) * S + qg) * 128 + hi * 8) + kc * 16);

    f32x16 ov[4];
#pragma unroll
    for (int dc = 0; dc < 4; ++dc)
#pragma unroll
        for (int r = 0; r < 16; ++r) ov[dc][r] = 0.f;
    float mrun = -3.0e38f, lrun = 0.f;

    const int g256 = tid & 255;
    const short* kg[4]; const short* vg[4]; int lb[4];
#pragma unroll
    for (int i = 0; i < 4; ++i) {
        int oo = (i * 256 + g256) * 8;
        lb[i] = (i * 256 + (g256 & ~63)) * 8;
        {
            int row = oo >> 7, col = oo & 127, ch = col >> 3;
            kg[i] = Kb + ((size_t)bhk * S + row) * 128 + ((ch ^ (row & 7)) << 3);
        }
        {
            int row = oo >> 6, col = oo & 63, ch = col >> 3;
            vg[i] = Vtb + ((size_t)bhk * 128 + row) * S + ((ch ^ (row & 7)) << 3);
        }
    }

#define TILE_IDX(it_) ((g == 0) ? (it_) : ((it_) < nB ? (it_) : 17 + (it_) - nB))
#define STAGE_TILE(jj, bb) do {                                                  \
        const int base_ = (jj) * 64;                                             \
        _Pragma("unroll")                                                        \
        for (int i_ = 0; i_ < 4; ++i_)                                           \
            gload_lds16(kg[i_] + (size_t)base_ * 128, &KV[g][bb][lb[i_]]);       \
        _Pragma("unroll")                                                        \
        for (int i_ = 0; i_ < 4; ++i_)                                           \
            gload_lds16(vg[i_] + base_, &KV[g][bb][8192 + lb[i_]]);              \
    } while (0)

#define WRITE_OUT(Q0_) do {                                                      \
        const float linv_ = gate / lrun;                                         \
        _Pragma("unroll")                                                        \
        for (int r_ = 0; r_ < 16; ++r_) {                                        \
            int cr_ = (r_ & 3) + 8 * (r_ >> 2) + 4 * hi;                         \
            float sc_ = __uint_as_float(                                         \
                (uint32_t)__builtin_amdgcn_ds_bpermute(cr_ << 2,                 \
                    (int)__float_as_uint(linv_)));                               \
            int qrow_ = (Q0_) + cr_;                                             \
            short* orow_ = attnb + ((size_t)(b * S) + qrow_) * 2048 + h * 128 + ql; \
            _Pragma("unroll")                                                    \
            for (int dc_ = 0; dc_ < 4; ++dc_)                                    \
                orow_[dc_ * 32] = (short)f2bf(ov[dc_][r_] * sc_);                \
        }                                                                        \
    } while (0)

    STAGE_TILE(0, 0);
    asm volatile("s_waitcnt vmcnt(0)");
    __syncthreads();

    int cur = 0;
    for (int it = 0; it < 17; ++it) {
        if (g == 1 && it == nB) {
            WRITE_OUT(q0);
            q0 = qtA * 32; qg = q0 + ql;
#pragma unroll
            for (int kc = 0; kc < 8; ++kc)
                qf[kc] = *(const s16x8*)(Qb + (((size_t)(b * 16 + h) * S + qg) * 128 + hi * 8) + kc * 16);
            mrun = -3.0e38f; lrun = 0.f;
#pragma unroll
            for (int dc = 0; dc < 4; ++dc)
#pragma unroll
                for (int r = 0; r < 16; ++r) ov[dc][r] = 0.f;
        }
        const int j = TILE_IDX(it);
        const bool active = (g == 0) ? true : (it < 16);
        {
            const int itn = it + 1;
            const bool nok = (itn < 17) && ((g == 0) ? true : (itn < 16));
            if (nok) { const int jn = TILE_IDX(itn); STAGE_TILE(jn, cur ^ 1); }
        }
        if (active) {
            const int j0 = j * 64;
            const short* Ks = &KV[g][cur][0];
            const short* Vs = &KV[g][cur][8192];
            const bool have1 = (j0 + 32 <= q0 + 31);
            const bool fsub0 = (j0 + 31 <= q0);
            const bool fsub1 = (j0 + 63 <= q0);
            f32x16 s0, s1;
#pragma unroll
            for (int r = 0; r < 16; ++r) { s0[r] = 0.f; s1[r] = 0.f; }
            __builtin_amdgcn_s_setprio(1);
#pragma unroll
            for (int kc = 0; kc < 8; ++kc) {
                const int c = kc * 2 + hi;
                s16x8 kf0 = *(const s16x8*)&Ks[ql * 128 + ((c ^ (ql & 7)) << 3)];
                s0 = mfma32(kf0, qf[kc], s0);
            }
            if (have1) {
#pragma unroll
                for (int kc = 0; kc < 8; ++kc) {
                    const int c = kc * 2 + hi;
                    const int kr = 32 + ql;
                    s16x8 kf1 = *(const s16x8*)&Ks[kr * 128 + ((c ^ (kr & 7)) << 3)];
                    s1 = mfma32(kf1, qf[kc], s1);
                }
            }
            __builtin_amdgcn_s_setprio(0);
            float p0[16], p1[16];
            if (fsub0) {
#pragma unroll
                for (int r = 0; r < 16; ++r) p0[r] = s0[r];
            } else {
#pragma unroll
                for (int r = 0; r < 16; ++r) {
                    int kvg = j0 + ((r & 3) + 8 * (r >> 2) + 4 * hi);
                    p0[r] = (kvg <= qg) ? s0[r] : -3.0e38f;
                }
            }
            if (have1) {
                if (fsub1) {
#pragma unroll
                    for (int r = 0; r < 16; ++r) p1[r] = s1[r];
                } else {
#pragma unroll
                    for (int r = 0; r < 16; ++r) {
                        int kvg = j0 + 32 + ((r & 3) + 8 * (r >> 2) + 4 * hi);
                        p1[r] = (kvg <= qg) ? s1[r] : -3.0e38f;
                    }
                }
            }
            float a0 = fmaxf(p0[0], p0[1]),  a1 = fmaxf(p0[2], p0[3]);
            float a2 = fmaxf(p0[4], p0[5]),  a3 = fmaxf(p0[6], p0[7]);
            float a4 = fmaxf(p0[8], p0[9]),  a5 = fmaxf(p0[10], p0[11]);
            float a6 = fmaxf(p0[12], p0[13]), a7 = fmaxf(p0[14], p0[15]);
            float pmax = fmaxf(fmaxf(fmaxf(a0, a1), fmaxf(a2, a3)),
                               fmaxf(fmaxf(a4, a5), fmaxf(a6, a7)));
            if (have1) {
                float b0 = fmaxf(p1[0], p1[1]),  b1 = fmaxf(p1[2], p1[3]);
                float b2 = fmaxf(p1[4], p1[5]),  b3 = fmaxf(p1[6], p1[7]);
                float b4 = fmaxf(p1[8], p1[9]),  b5 = fmaxf(p1[10], p1[11]);
                float b6 = fmaxf(p1[12], p1[13]), b7 = fmaxf(p1[14], p1[15]);
                pmax = fmaxf(pmax, fmaxf(fmaxf(fmaxf(b0, b1), fmaxf(b2, b3)),
                                         fmaxf(fmaxf(b4, b5), fmaxf(b6, b7))));
            }
            pmax = cross_max(pmax);
            if (__any(pmax - mrun > THR)) {
                float mnew = fmaxf(mrun, pmax);
                float alpha = __builtin_exp2f((mrun - mnew) * cs);
                lrun *= alpha;
#pragma unroll
                for (int r = 0; r < 16; ++r) {
                    int cr = (r & 3) + 8 * (r >> 2) + 4 * hi;
                    float ar = __uint_as_float(
                        (uint32_t)__builtin_amdgcn_ds_bpermute(cr << 2, (int)__float_as_uint(alpha)));
                    ov[0][r] *= ar; ov[1][r] *= ar; ov[2][r] *= ar; ov[3][r] *= ar;
                }
                mrun = mnew;
            }
#pragma unroll
            for (int r = 0; r < 16; ++r) p0[r] = __builtin_exp2f((p0[r] - mrun) * cs);
            float ps;
            {
                float t0 = (p0[0] + p0[1]) + (p0[2] + p0[3]);
                float t1 = (p0[4] + p0[5]) + (p0[6] + p0[7]);
                float t2 = (p0[8] + p0[9]) + (p0[10] + p0[11]);
                float t3 = (p0[12] + p0[13]) + (p0[14] + p0[15]);
                ps = (t0 + t1) + (t2 + t3);
            }
            if (have1) {
#pragma unroll
                for (int r = 0; r < 16; ++r) p1[r] = __builtin_exp2f((p1[r] - mrun) * cs);
                float t0 = (p1[0] + p1[1]) + (p1[2] + p1[3]);
                float t1 = (p1[4] + p1[5]) + (p1[6] + p1[7]);
                float t2 = (p1[8] + p1[9]) + (p1[10] + p1[11]);
                float t3 = (p1[12] + p1[13]) + (p1[14] + p1[15]);
                ps += (t0 + t1) + (t2 + t3);
            }
            lrun += cross_sum(ps);
            union { uint32_t u[4]; s16x8 v; } f00, f01, f10, f11;
            {
                uint32_t w0 = cvtpk_bf16(p0[0], p0[1]),   w1 = cvtpk_bf16(p0[2], p0[3]);
                uint32_t w2 = cvtpk_bf16(p0[4], p0[5]),   w3 = cvtpk_bf16(p0[6], p0[7]);
                uint32_t w4 = cvtpk_bf16(p0[8], p0[9]),   w5 = cvtpk_bf16(p0[10], p0[11]);
                uint32_t w6 = cvtpk_bf16(p0[12], p0[13]), w7 = cvtpk_bf16(p0[14], p0[15]);
                u32x2 r02 = pl32swap(w0, w2); f00.u[0] = r02[0]; f00.u[2] = r02[1];
                u32x2 r13 = pl32swap(w1, w3); f00.u[1] = r13[0]; f00.u[3] = r13[1];
                u32x2 r46 = pl32swap(w4, w6); f01.u[0] = r46[0]; f01.u[2] = r46[1];
                u32x2 r57 = pl32swap(w5, w7); f01.u[1] = r57[0]; f01.u[3] = r57[1];
            }
            if (have1) {
                uint32_t w0 = cvtpk_bf16(p1[0], p1[1]),   w1 = cvtpk_bf16(p1[2], p1[3]);
                uint32_t w2 = cvtpk_bf16(p1[4], p1[5]),   w3 = cvtpk_bf16(p1[6], p1[7]);
                uint32_t w4 = cvtpk_bf16(p1[8], p1[9]),   w5 = cvtpk_bf16(p1[10], p1[11]);
                uint32_t w6 = cvtpk_bf16(p1[12], p1[13]), w7 = cvtpk_bf16(p1[14], p1[15]);
                u32x2 r02 = pl32swap(w0, w2); f10.u[0] = r02[0]; f10.u[2] = r02[1];
                u32x2 r13 = pl32swap(w1, w3); f10.u[1] = r13[0]; f10.u[3] = r13[1];
                u32x2 r46 = pl32swap(w4, w6); f11.u[0] = r46[0]; f11.u[2] = r46[1];
                u32x2 r57 = pl32swap(w5, w7); f11.u[1] = r57[0]; f11.u[3] = r57[1];
            }
            __builtin_amdgcn_s_setprio(1);
#pragma unroll
            for (int dc = 0; dc < 4; ++dc) {
                const int dd = dc * 32 + ql;
                const int sw = (dd & 7);
                s16x8 v0 = *(const s16x8*)&Vs[dd * 64 + (((hi) ^ sw) << 3)];
                ov[dc] = mfma32(f00.v, v0, ov[dc]);
                s16x8 v1 = *(const s16x8*)&Vs[dd * 64 + (((2 + hi) ^ sw) << 3)];
                ov[dc] = mfma32(f01.v, v1, ov[dc]);
                if (have1) {
                    s16x8 v2 = *(const s16x8*)&Vs[dd * 64 + (((4 + hi) ^ sw) << 3)];
                    ov[dc] = mfma32(f10.v, v2, ov[dc]);
                    s16x8 v3 = *(const s16x8*)&Vs[dd * 64 + (((6 + hi) ^ sw) << 3)];
                    ov[dc] = mfma32(f11.v, v3, ov[dc]);
                }
            }
            __builtin_amdgcn_s_setprio(0);
        }
        asm volatile("s_waitcnt vmcnt(0)");
        __syncthreads();
        cur ^= 1;
    }

    float* mb = (float*)&KV[0][0][0];
    if (g == 1) {
#pragma unroll
        for (int dc = 0; dc < 4; ++dc)
#pragma unroll
            for (int r = 0; r < 16; ++r)
                mb[hw * 4096 + lane * 64 + dc * 16 + r] = ov[dc][r];
        mb[16384 + hw * 64 + lane] = mrun;
        mb[16640 + hw * 64 + lane] = lrun;
    }
    __syncthreads();
    if (g == 0) {
        const float m1 = mb[16384 + hw * 64 + lane];
        const float l1 = mb[16640 + hw * 64 + lane];
        const float mm = fmaxf(mrun, m1);
        const float al0 = __builtin_exp2f((mrun - mm) * cs);
        const float al1 = __builtin_exp2f((m1 - mm) * cs);
        lrun = lrun * al0 + l1 * al1;
#pragma unroll
        for (int r = 0; r < 16; ++r) {
            int cr = (r & 3) + 8 * (r >> 2) + 4 * hi;
            float a0r = __uint_as_float(
                (uint32_t)__builtin_amdgcn_ds_bpermute(cr << 2, (int)__float_as_uint(al0)));
            float a1r = __uint_as_float(
                (uint32_t)__builtin_amdgcn_ds_bpermute(cr << 2, (int)__float_as_uint(al1)));
#pragma unroll
            for (int dc = 0; dc < 4; ++dc)
                ov[dc][r] = ov[dc][r] * a0r + mb[hw * 4096 + lane * 64 + dc * 16 + r] * a1r;
        }
        WRITE_OUT(q0);
    }
#undef TILE_IDX
#undef STAGE_TILE
#undef WRITE_OUT
}

// ---------- launch ----------
extern "C" void kernel_launch(void* const* d_in, const int* in_sizes, int n_in,
                              void* d_out, int out_size, void* d_ws, size_t ws_size,
                              hipStream_t stream) {
    const float* x  = (const float*)d_in[0];
    const float* Wq = (const float*)d_in[1];
    const float* bq = (const float*)d_in[2];
    const float* Wk = (const float*)d_in[3];
    const float* bk = (const float*)d_in[4];
    const float* Wv = (const float*)d_in[5];
    const float* bv = (const float*)d_in[6];
    const float* Wo = (const float*)d_in[7];
    const float* bo = (const float*)d_in[8];
    const float* qn = (const float*)d_in[9];
    const float* kn = (const float*)d_in[10];
    const float* gl = (const float*)d_in[11];
    const int* sp   = (const int*)d_in[13];
    float* out = (float*)d_out;

    char* ws = (char*)d_ws;
    const size_t NEED = 96481280;
    if (ws_size < NEED) return;
    short* xb    = (short*)(ws + 0);            // 16 MiB, reused as Qb
    short* wqkvT = (short*)(ws + 16777216);     // 12 MiB
    short* woT   = (short*)(ws + 29360128);     // 8 MiB
    float* bqkv  = (float*)(ws + 37748736);     // 12 KiB
    short* Yb    = (short*)(ws + 37761024);     // 24 MiB bf16, head reused as attnb
    short* Kb    = (short*)(ws + 88092672);     // 4 MiB
    short* Vtb   = (short*)(ws + 92286976);     // 4 MiB
    short* Qb    = xb;
    short* attnb = Yb;

    f32_to_bf16_k<<<4096, 256, 0, stream>>>(x, xb, 1048576);
    transpose_f32_bf16_k<<<dim3(32, 32, 1), 256, 0, stream>>>(Wq, 0, 2048, wqkvT, 0, 2048);
    transpose_f32_bf16_k<<<dim3(8, 32, 1), 256, 0, stream>>>(Wk, 0, 512, wqkvT + (size_t)2048 * 2048, 0, 2048);
    transpose_f32_bf16_k<<<dim3(8, 32, 1), 256, 0, stream>>>(Wv, 0, 512, wqkvT + (size_t)2560 * 2048, 0, 2048);
    transpose_f32_bf16_k<<<dim3(32, 32, 1), 256, 0, stream>>>(Wo, 0, 2048, woT, 0, 2048);
    concat_bias_k<<<12, 256, 0, stream>>>(bq, bk, bv, bqkv);
    gemm256_k<0, true, 3><<<dim3(16, 16), 512, 0, stream>>>(xb, wqkvT, bqkv, Yb, 4096, 3072, 2048);
    qkv_post_k<<<4096, 256, 0, stream>>>(Yb, qn, kn, sp, Qb, Kb);
    transpose_bf16_k<<<dim3(8, 32, 2), 256, 0, stream>>>(
        Yb + 2560, (size_t)2048 * 3072, 3072, Vtb, (size_t)512 * 2048, 2048);
    attn_fwd_k<<<dim3(8, 32), 512, 0, stream>>>(Qb, Kb, Vtb, gl, attnb);
    gemm256_k<1, false, 2><<<dim3(16, 16), 512, 0, stream>>>(attnb, woT, bo, out, 4096, 2048, 2048);
}

// Round 14
// 193.172 us; speedup vs baseline: 1.1012x; 1.1012x over previous
//
#include <hip/hip_runtime.h>
#include <hip/hip_bf16.h>
#include <stdint.h>

#define DEV __device__ __forceinline__

typedef short     s16x8  __attribute__((ext_vector_type(8)));
typedef __bf16    bf16v8 __attribute__((ext_vector_type(8)));
typedef float     f32x4  __attribute__((ext_vector_type(4)));
typedef float     f32x16 __attribute__((ext_vector_type(16)));
typedef unsigned int u32x2 __attribute__((ext_vector_type(2)));

// ---------- helpers ----------
DEV unsigned short f2bf(float x) {
    uint32_t u = __float_as_uint(x);
    uint32_t r = (u + 0x7FFFu + ((u >> 16) & 1u)) >> 16;
    return (unsigned short)r;
}
DEV float bf2f(uint32_t u) { return __uint_as_float(u << 16); }

DEV void gload_lds16(const void* g, void* l) {
    __builtin_amdgcn_global_load_lds((const __attribute__((address_space(1))) void*)g,
                                     (__attribute__((address_space(3))) void*)l,
                                     16, 0, 0);
}

DEV f32x4 mfma16(s16x8 a, s16x8 b, f32x4 c) {
    return __builtin_amdgcn_mfma_f32_16x16x32_bf16(
        __builtin_bit_cast(bf16v8, a), __builtin_bit_cast(bf16v8, b), c, 0, 0, 0);
}
DEV f32x16 mfma32(s16x8 a, s16x8 b, f32x16 c) {
    return __builtin_amdgcn_mfma_f32_32x32x16_bf16(
        __builtin_bit_cast(bf16v8, a), __builtin_bit_cast(bf16v8, b), c, 0, 0, 0);
}

DEV uint32_t cvtpk_bf16(float lo, float hi) {
    uint32_t r;
    asm volatile("v_cvt_pk_bf16_f32 %0, %1, %2" : "=v"(r) : "v"(lo), "v"(hi));
    return r;
}

DEV u32x2 pl32swap(uint32_t a, uint32_t b) {
    return __builtin_amdgcn_permlane32_swap(a, b, false, false);
}
DEV float cross_max(float x) {
    u32x2 r = pl32swap(__float_as_uint(x), __float_as_uint(x));
    return fmaxf(__uint_as_float(r[0]), __uint_as_float(r[1]));
}
DEV float cross_sum(float x) {
    u32x2 r = pl32swap(__float_as_uint(x), __float_as_uint(x));
    return __uint_as_float(r[0]) + __uint_as_float(r[1]);
}

DEV void barx() {
    asm volatile("" ::: "memory");
    __builtin_amdgcn_s_barrier();
    __builtin_amdgcn_sched_barrier(0);
    asm volatile("" ::: "memory");
}

// ---------- elementwise f32 -> bf16 ----------
__global__ void f32_to_bf16_k(const float* __restrict__ in, short* __restrict__ out, int n8) {
    int i = blockIdx.x * blockDim.x + threadIdx.x;
    if (i >= n8) return;
    const float4 a = *(const float4*)(in + (size_t)i * 8);
    const float4 b = *(const float4*)(in + (size_t)i * 8 + 4);
    uint4 w;
    w.x = (uint32_t)f2bf(a.x) | ((uint32_t)f2bf(a.y) << 16);
    w.y = (uint32_t)f2bf(a.z) | ((uint32_t)f2bf(a.w) << 16);
    w.z = (uint32_t)f2bf(b.x) | ((uint32_t)f2bf(b.y) << 16);
    w.w = (uint32_t)f2bf(b.z) | ((uint32_t)f2bf(b.w) << 16);
    *(uint4*)(out + (size_t)i * 8) = w;
}

// ---------- tiled transpose f32 (R x C) -> bf16 (C x R) ----------
__global__ __launch_bounds__(256) void transpose_f32_bf16_k(
    const float* __restrict__ in, size_t in_batch, int ld_in,
    short* __restrict__ out, size_t out_batch, int ld_out) {
    __shared__ float tile[64][65];
    const float* ip = in + (size_t)blockIdx.z * in_batch;
    short* op = out + (size_t)blockIdx.z * out_batch;
    const int c0 = blockIdx.x * 64, r0 = blockIdx.y * 64;
    const int t = threadIdx.x;
    const int cc4 = (t & 15) * 4;
    const int rr  = t >> 4;
#pragma unroll
    for (int p = 0; p < 4; ++p) {
        int r = rr + p * 16;
        float4 v = *(const float4*)(ip + (size_t)(r0 + r) * ld_in + c0 + cc4);
        tile[r][cc4 + 0] = v.x; tile[r][cc4 + 1] = v.y;
        tile[r][cc4 + 2] = v.z; tile[r][cc4 + 3] = v.w;
    }
    __syncthreads();
#pragma unroll
    for (int p = 0; p < 4; ++p) {
        int oc  = (t >> 4) + p * 16;
        int rr4 = (t & 15) * 4;
        ushort4 w;
        w.x = f2bf(tile[rr4 + 0][oc]);
        w.y = f2bf(tile[rr4 + 1][oc]);
        w.z = f2bf(tile[rr4 + 2][oc]);
        w.w = f2bf(tile[rr4 + 3][oc]);
        *(ushort4*)(op + (size_t)(c0 + oc) * ld_out + r0 + rr4) = w;
    }
}

// ---------- tiled transpose bf16 (R x C) -> bf16 (C x R) ----------
__global__ __launch_bounds__(256) void transpose_bf16_k(
    const short* __restrict__ in, size_t in_batch, int ld_in,
    short* __restrict__ out, size_t out_batch, int ld_out) {
    __shared__ short tile[64][72];
    const short* ip = in + (size_t)blockIdx.z * in_batch;
    short* op = out + (size_t)blockIdx.z * out_batch;
    const int c0 = blockIdx.x * 64, r0 = blockIdx.y * 64;
    const int t = threadIdx.x;
    const int cc = (t & 7) * 8;
    const int rr = t >> 3;
#pragma unroll
    for (int p = 0; p < 2; ++p) {
        int r = rr + p * 32;
        s16x8 v = *(const s16x8*)(ip + (size_t)(r0 + r) * ld_in + c0 + cc);
        *(s16x8*)&tile[r][cc] = v;
    }
    __syncthreads();
    const int oc = t >> 2;
    const int rb = (t & 3) * 16;
    s16x8 w0, w1;
#pragma unroll
    for (int j = 0; j < 8; ++j) w0[j] = tile[rb + j][oc];
#pragma unroll
    for (int j = 0; j < 8; ++j) w1[j] = tile[rb + 8 + j][oc];
    *(s16x8*)(op + (size_t)(c0 + oc) * ld_out + r0 + rb) = w0;
    *(s16x8*)(op + (size_t)(c0 + oc) * ld_out + r0 + rb + 8) = w1;
}

// ---------- bias concat ----------
__global__ void concat_bias_k(const float* __restrict__ bq, const float* __restrict__ bk,
                              const float* __restrict__ bv, float* __restrict__ o) {
    int i = blockIdx.x * 256 + threadIdx.x;
    if (i < 2048)       o[i] = bq[i];
    else if (i < 2560)  o[i] = bk[i - 2048];
    else if (i < 3072)  o[i] = bv[i - 2560];
}

// ---------- GEMM v5 (r12-proven, 194.6 us config): 2-phase counted-vmcnt ----
template<int TAG, bool OUTBF, int NF>
__global__ __launch_bounds__(512, 2) void gemm256_k(
    const short* __restrict__ A, const short* __restrict__ Bt,
    const float* __restrict__ bias, void* __restrict__ Cv,
    int M, int N, int K) {
    __shared__ short As[2][16384];
    __shared__ short Bs[2][NF * 4096];
    const int tid = threadIdx.x;
    const int gx = gridDim.x;
    const int nwg = gx * gridDim.y;
    const int flat = blockIdx.y * gx + blockIdx.x;
    const int cpx = nwg >> 3;
    const int swz = (flat & 7) * cpx + (flat >> 3);
    const int m0 = (swz / gx) * 256, n0 = (swz % gx) * (NF * 64);
    const int lane = tid & 63, wid = tid >> 6;
    const int wm = wid >> 2, wn = wid & 3;
    const int lr = lane & 15, lg = lane >> 4;

    const int srow = tid >> 3;
    const int schunk = ((tid & 7) ^ (srow & 7)) << 3;
    const short* Ag = A  + (size_t)(m0 + srow) * K + schunk;
    const short* Bg = Bt + (size_t)(n0 + srow) * K + schunk;
    const int lwb = (tid & ~63) * 8;

    f32x4 acc[8][NF];
#pragma unroll
    for (int fr = 0; fr < 8; ++fr)
#pragma unroll
        for (int fc = 0; fc < NF; ++fc)
#pragma unroll
            for (int r = 0; r < 4; ++r) acc[fr][fc][r] = 0.f;

    const int nk = K >> 6;

#define SA(u, kt, dd) gload_lds16(Ag + (size_t)(u) * 64 * K + (kt) * 64, &As[dd][(u) * 4096 + lwb])
#define SB(u, kt, dd) gload_lds16(Bg + (size_t)(u) * 64 * K + (kt) * 64, &Bs[dd][(u) * 4096 + lwb])

    SA(0, 0, 0); SA(1, 0, 0); SA(2, 0, 0); SA(3, 0, 0);
#pragma unroll
    for (int u = 0; u < NF; ++u) SB(u, 0, 0);
    asm volatile("s_waitcnt vmcnt(0)" ::: "memory");
    barx();

    for (int t = 0; t < nk; ++t) {
        const int d = t & 1, e = d ^ 1;
        const bool more = (t + 1 < nk);
        // ---- phase 0 (mh=0) ----
        {
            s16x8 af[2][4], bf[2][NF];
#pragma unroll
            for (int ks = 0; ks < 2; ++ks) {
                const int csw = ((ks * 4 + lg) ^ (lr & 7)) * 8;
#pragma unroll
                for (int i = 0; i < 4; ++i)
                    af[ks][i] = *(const s16x8*)&As[d][(wm * 128 + i * 16 + lr) * 64 + csw];
#pragma unroll
                for (int j = 0; j < NF; ++j)
                    bf[ks][j] = *(const s16x8*)&Bs[d][(wn * (NF * 16) + j * 16 + lr) * 64 + csw];
            }
            if (more) {
                SA(0, t + 1, e); SA(2, t + 1, e);
#pragma unroll
                for (int u = 0; u < NF; ++u) SB(u, t + 1, e);
            }
            __builtin_amdgcn_s_setprio(1);
#pragma unroll
            for (int ks = 0; ks < 2; ++ks)
#pragma unroll
                for (int i = 0; i < 4; ++i)
#pragma unroll
                    for (int j = 0; j < NF; ++j)
                        acc[i][j] = mfma16(af[ks][i], bf[ks][j], acc[i][j]);
            __builtin_amdgcn_s_setprio(0);
            if (more) { asm volatile("s_waitcnt vmcnt(%0)" :: "i"(NF + 2) : "memory"); }
            else      { asm volatile("s_waitcnt vmcnt(0)" ::: "memory"); }
            barx();
        }
        // ---- phase 1 (mh=1) ----
        {
            s16x8 af[2][4], bf[2][NF];
#pragma unroll
            for (int ks = 0; ks < 2; ++ks) {
                const int csw = ((ks * 4 + lg) ^ (lr & 7)) * 8;
#pragma unroll
                for (int i = 0; i < 4; ++i)
                    af[ks][i] = *(const s16x8*)&As[d][(wm * 128 + 64 + i * 16 + lr) * 64 + csw];
#pragma unroll
                for (int j = 0; j < NF; ++j)
                    bf[ks][j] = *(const s16x8*)&Bs[d][(wn * (NF * 16) + j * 16 + lr) * 64 + csw];
            }
            if (more) { SA(1, t + 1, e); SA(3, t + 1, e); }
            __builtin_amdgcn_s_setprio(1);
#pragma unroll
            for (int ks = 0; ks < 2; ++ks)
#pragma unroll
                for (int i = 0; i < 4; ++i)
#pragma unroll
                    for (int j = 0; j < NF; ++j)
                        acc[4 + i][j] = mfma16(af[ks][i], bf[ks][j], acc[4 + i][j]);
            __builtin_amdgcn_s_setprio(0);
            if (more) {
                asm volatile("s_waitcnt vmcnt(2)" ::: "memory");
                barx();
            }
        }
    }
#undef SA
#undef SB

#pragma unroll
    for (int fr = 0; fr < 8; ++fr) {
        const int row = m0 + wm * 128 + fr * 16 + lg * 4;
#pragma unroll
        for (int fc = 0; fc < NF; ++fc) {
            const int col = n0 + wn * (NF * 16) + fc * 16 + lr;
            const float bbv = bias[col];
            if constexpr (OUTBF) {
                short* Cs = (short*)Cv;
#pragma unroll
                for (int r = 0; r < 4; ++r)
                    Cs[(size_t)(row + r) * N + col] = (short)f2bf(acc[fr][fc][r] + bbv);
            } else {
                float* Cf = (float*)Cv;
#pragma unroll
                for (int r = 0; r < 4; ++r)
                    Cf[(size_t)(row + r) * N + col] = acc[fr][fc][r] + bbv;
            }
        }
    }
}

// ---------- rmsnorm + rope + head layout for Q,K (bf16 Y input) ----------
// Q is pre-scaled by CS = log2(e)/sqrt(128) so attn softmax uses exp2 directly.
__global__ __launch_bounds__(256) void qkv_post_k(
    const short* __restrict__ Y, const float* __restrict__ qn_w,
    const float* __restrict__ kn_w, const int* __restrict__ start_pos,
    short* __restrict__ Qb, short* __restrict__ Kb) {
    const int m = blockIdx.x;
    const int b = m >> 11, s = m & 2047;
    const short* y = Y + (size_t)m * 3072;
    const int tid = threadIdx.x;
    const float CS = 0.12751745f;   // log2(e) / sqrt(128)

    s16x8 qv = *(const s16x8*)(y + tid * 8);
    float qn[8];
#pragma unroll
    for (int j = 0; j < 8; ++j) qn[j] = bf2f((uint32_t)(unsigned short)qv[j]);
    const uint32_t kvu = *(const uint32_t*)(y + 2048 + tid * 2);
    float k1 = bf2f(kvu & 0xffffu), k2 = bf2f(kvu >> 16);

    float ssq = qn[0]*qn[0] + qn[1]*qn[1] + qn[2]*qn[2] + qn[3]*qn[3]
              + qn[4]*qn[4] + qn[5]*qn[5] + qn[6]*qn[6] + qn[7]*qn[7];
    float ssk = k1 * k1 + k2 * k2;
#pragma unroll
    for (int off = 1; off < 64; off <<= 1) {
        ssq += __shfl_xor(ssq, off);
        ssk += __shfl_xor(ssk, off);
    }
    __shared__ float red[8];
    if ((tid & 63) == 0) { red[tid >> 6] = ssq; red[4 + (tid >> 6)] = ssk; }
    __syncthreads();
    const float tq = red[0] + red[1] + red[2] + red[3];
    const float tk = red[4] + red[5] + red[6] + red[7];
    const float rq = rsqrtf(tq * (1.f / 2048.f) + 1.1920929e-07f) * CS;  // fold CS into Q
    const float rk = rsqrtf(tk * (1.f / 512.f) + 1.1920929e-07f);
    const int pos = start_pos[0] + s;

#pragma unroll
    for (int j = 0; j < 8; ++j) qn[j] *= rq * qn_w[tid * 8 + j];
    const int hq = tid >> 4;
    const int din = (tid * 8) & 127;
    unsigned short ob[8];
#pragma unroll
    for (int j = 0; j < 4; ++j) {
        int tt = (din >> 1) + j;
        float inv = __builtin_exp2f(-0.20762050f * (float)tt);
        float ang = (float)pos * inv;
        float sn, cn;
        __sincosf(ang, &sn, &cn);
        float x1 = qn[2 * j], x2 = qn[2 * j + 1];
        ob[2 * j]     = f2bf(x1 * cn - x2 * sn);
        ob[2 * j + 1] = f2bf(x1 * sn + x2 * cn);
    }
    short* qdst = Qb + (((size_t)(b * 16 + hq) * 2048 + s) * 128 + din);
    uint4 w;
    w.x = (uint32_t)ob[0] | ((uint32_t)ob[1] << 16);
    w.y = (uint32_t)ob[2] | ((uint32_t)ob[3] << 16);
    w.z = (uint32_t)ob[4] | ((uint32_t)ob[5] << 16);
    w.w = (uint32_t)ob[6] | ((uint32_t)ob[7] << 16);
    *(uint4*)qdst = w;

    const int colk = tid * 2;
    const int hk = colk >> 7, dk = colk & 127;
    float kk1 = k1 * rk * kn_w[colk], kk2 = k2 * rk * kn_w[colk + 1];
    {
        int tt = dk >> 1;
        float inv = __builtin_exp2f(-0.20762050f * (float)tt);
        float ang = (float)pos * inv;
        float sn, cn;
        __sincosf(ang, &sn, &cn);
        float r1 = kk1 * cn - kk2 * sn, r2 = kk1 * sn + kk2 * cn;
        short* kdst = Kb + (((size_t)(b * 4 + hk) * 2048 + s) * 128 + dk);
        *(uint32_t*)kdst = (uint32_t)f2bf(r1) | ((uint32_t)f2bf(r2) << 16);
    }
}

// ---------- flash attention v8: v7 + pre-scaled Q (exp2 direct) ----------
__global__ __launch_bounds__(512, 1) void attn_fwd_k(
    const short* __restrict__ Qb, const short* __restrict__ Kb,
    const short* __restrict__ Vtb, const float* __restrict__ gate_logits,
    short* __restrict__ attnb) {
    const int S = 2048;
    __shared__ short KV[2][2][16384];
    const int tid = threadIdx.x, lane = tid & 63;
    const int wid = tid >> 6;
    const int g = wid >> 2;
    const int hw = wid & 3;
    const int y = blockIdx.y;
    const int bhk = blockIdx.x;
    const int b = bhk >> 2, hk = bhk & 3;
    const int h = hk * 4 + hw;
    const int qtA = 63 - y, qtB = y;
    const int nA = (qtA + 2) >> 1, nB = (qtB + 2) >> 1;
    const int ql = lane & 31, hi = lane >> 5;
    const float THR = 11.5416f;         // 8 * log2(e), scores already in log2 units
    const float gl = gate_logits[h];
    const float gate = 1.f / (1.f + __expf(-gl));

    int q0 = (g == 0 ? qtA : qtB) * 32;
    int qg = q0 + ql;

    s16x8 qf[8];
#pragma unroll
    for (int kc = 0; kc < 8; ++kc)
        qf[kc] = *(const s16x8*)(Qb + (((size_t)(b * 16 + h) * S + qg) * 128 + hi * 8) + kc * 16);

    f32x16 ov[4];
#pragma unroll
    for (int dc = 0; dc < 4; ++dc)
#pragma unroll
        for (int r = 0; r < 16; ++r) ov[dc][r] = 0.f;
    float mrun = -3.0e38f, lrun = 0.f;

    const int g256 = tid & 255;
    const short* kg[4]; const short* vg[4]; int lb[4];
#pragma unroll
    for (int i = 0; i < 4; ++i) {
        int oo = (i * 256 + g256) * 8;
        lb[i] = (i * 256 + (g256 & ~63)) * 8;
        {
            int row = oo >> 7, col = oo & 127, ch = col >> 3;
            kg[i] = Kb + ((size_t)bhk * S + row) * 128 + ((ch ^ (row & 7)) << 3);
        }
        {
            int row = oo >> 6, col = oo & 63, ch = col >> 3;
            vg[i] = Vtb + ((size_t)bhk * 128 + row) * S + ((ch ^ (row & 7)) << 3);
        }
    }

#define TILE_IDX(it_) ((g == 0) ? (it_) : ((it_) < nB ? (it_) : 17 + (it_) - nB))
#define STAGE_TILE(jj, bb) do {                                                  \
        const int base_ = (jj) * 64;                                             \
        _Pragma("unroll")                                                        \
        for (int i_ = 0; i_ < 4; ++i_)                                           \
            gload_lds16(kg[i_] + (size_t)base_ * 128, &KV[g][bb][lb[i_]]);       \
        _Pragma("unroll")                                                        \
        for (int i_ = 0; i_ < 4; ++i_)                                           \
            gload_lds16(vg[i_] + base_, &KV[g][bb][8192 + lb[i_]]);              \
    } while (0)

#define WRITE_OUT(Q0_) do {                                                      \
        const float linv_ = gate / lrun;                                         \
        _Pragma("unroll")                                                        \
        for (int r_ = 0; r_ < 16; ++r_) {                                        \
            int cr_ = (r_ & 3) + 8 * (r_ >> 2) + 4 * hi;                         \
            float sc_ = __uint_as_float(                                         \
                (uint32_t)__builtin_amdgcn_ds_bpermute(cr_ << 2,                 \
                    (int)__float_as_uint(linv_)));                               \
            int qrow_ = (Q0_) + cr_;                                             \
            short* orow_ = attnb + ((size_t)(b * S) + qrow_) * 2048 + h * 128 + ql; \
            _Pragma("unroll")                                                    \
            for (int dc_ = 0; dc_ < 4; ++dc_)                                    \
                orow_[dc_ * 32] = (short)f2bf(ov[dc_][r_] * sc_);                \
        }                                                                        \
    } while (0)

    STAGE_TILE(0, 0);
    asm volatile("s_waitcnt vmcnt(0)");
    __syncthreads();

    int cur = 0;
    for (int it = 0; it < 17; ++it) {
        if (g == 1 && it == nB) {
            WRITE_OUT(q0);
            q0 = qtA * 32; qg = q0 + ql;
#pragma unroll
            for (int kc = 0; kc < 8; ++kc)
                qf[kc] = *(const s16x8*)(Qb + (((size_t)(b * 16 + h) * S + qg) * 128 + hi * 8) + kc * 16);
            mrun = -3.0e38f; lrun = 0.f;
#pragma unroll
            for (int dc = 0; dc < 4; ++dc)
#pragma unroll
                for (int r = 0; r < 16; ++r) ov[dc][r] = 0.f;
        }
        const int j = TILE_IDX(it);
        const bool active = (g == 0) ? true : (it < 16);
        {
            const int itn = it + 1;
            const bool nok = (itn < 17) && ((g == 0) ? true : (itn < 16));
            if (nok) { const int jn = TILE_IDX(itn); STAGE_TILE(jn, cur ^ 1); }
        }
        if (active) {
            const int j0 = j * 64;
            const short* Ks = &KV[g][cur][0];
            const short* Vs = &KV[g][cur][8192];
            const bool have1 = (j0 + 32 <= q0 + 31);
            const bool fsub0 = (j0 + 31 <= q0);
            const bool fsub1 = (j0 + 63 <= q0);
            f32x16 s0, s1;
#pragma unroll
            for (int r = 0; r < 16; ++r) { s0[r] = 0.f; s1[r] = 0.f; }
            __builtin_amdgcn_s_setprio(1);
#pragma unroll
            for (int kc = 0; kc < 8; ++kc) {
                const int c = kc * 2 + hi;
                s16x8 kf0 = *(const s16x8*)&Ks[ql * 128 + ((c ^ (ql & 7)) << 3)];
                s0 = mfma32(kf0, qf[kc], s0);
            }
            if (have1) {
#pragma unroll
                for (int kc = 0; kc < 8; ++kc) {
                    const int c = kc * 2 + hi;
                    const int kr = 32 + ql;
                    s16x8 kf1 = *(const s16x8*)&Ks[kr * 128 + ((c ^ (kr & 7)) << 3)];
                    s1 = mfma32(kf1, qf[kc], s1);
                }
            }
            __builtin_amdgcn_s_setprio(0);
            float p0[16], p1[16];
            if (fsub0) {
#pragma unroll
                for (int r = 0; r < 16; ++r) p0[r] = s0[r];
            } else {
#pragma unroll
                for (int r = 0; r < 16; ++r) {
                    int kvg = j0 + ((r & 3) + 8 * (r >> 2) + 4 * hi);
                    p0[r] = (kvg <= qg) ? s0[r] : -3.0e38f;
                }
            }
            if (have1) {
                if (fsub1) {
#pragma unroll
                    for (int r = 0; r < 16; ++r) p1[r] = s1[r];
                } else {
#pragma unroll
                    for (int r = 0; r < 16; ++r) {
                        int kvg = j0 + 32 + ((r & 3) + 8 * (r >> 2) + 4 * hi);
                        p1[r] = (kvg <= qg) ? s1[r] : -3.0e38f;
                    }
                }
            }
            float a0 = fmaxf(p0[0], p0[1]),  a1 = fmaxf(p0[2], p0[3]);
            float a2 = fmaxf(p0[4], p0[5]),  a3 = fmaxf(p0[6], p0[7]);
            float a4 = fmaxf(p0[8], p0[9]),  a5 = fmaxf(p0[10], p0[11]);
            float a6 = fmaxf(p0[12], p0[13]), a7 = fmaxf(p0[14], p0[15]);
            float pmax = fmaxf(fmaxf(fmaxf(a0, a1), fmaxf(a2, a3)),
                               fmaxf(fmaxf(a4, a5), fmaxf(a6, a7)));
            if (have1) {
                float b0 = fmaxf(p1[0], p1[1]),  b1 = fmaxf(p1[2], p1[3]);
                float b2 = fmaxf(p1[4], p1[5]),  b3 = fmaxf(p1[6], p1[7]);
                float b4 = fmaxf(p1[8], p1[9]),  b5 = fmaxf(p1[10], p1[11]);
                float b6 = fmaxf(p1[12], p1[13]), b7 = fmaxf(p1[14], p1[15]);
                pmax = fmaxf(pmax, fmaxf(fmaxf(fmaxf(b0, b1), fmaxf(b2, b3)),
                                         fmaxf(fmaxf(b4, b5), fmaxf(b6, b7))));
            }
            pmax = cross_max(pmax);
            if (__any(pmax - mrun > THR)) {
                float mnew = fmaxf(mrun, pmax);
                float alpha = __builtin_exp2f(mrun - mnew);
                lrun *= alpha;
#pragma unroll
                for (int r = 0; r < 16; ++r) {
                    int cr = (r & 3) + 8 * (r >> 2) + 4 * hi;
                    float ar = __uint_as_float(
                        (uint32_t)__builtin_amdgcn_ds_bpermute(cr << 2, (int)__float_as_uint(alpha)));
                    ov[0][r] *= ar; ov[1][r] *= ar; ov[2][r] *= ar; ov[3][r] *= ar;
                }
                mrun = mnew;
            }
#pragma unroll
            for (int r = 0; r < 16; ++r) p0[r] = __builtin_exp2f(p0[r] - mrun);
            float ps;
            {
                float t0 = (p0[0] + p0[1]) + (p0[2] + p0[3]);
                float t1 = (p0[4] + p0[5]) + (p0[6] + p0[7]);
                float t2 = (p0[8] + p0[9]) + (p0[10] + p0[11]);
                float t3 = (p0[12] + p0[13]) + (p0[14] + p0[15]);
                ps = (t0 + t1) + (t2 + t3);
            }
            if (have1) {
#pragma unroll
                for (int r = 0; r < 16; ++r) p1[r] = __builtin_exp2f(p1[r] - mrun);
                float t0 = (p1[0] + p1[1]) + (p1[2] + p1[3]);
                float t1 = (p1[4] + p1[5]) + (p1[6] + p1[7]);
                float t2 = (p1[8] + p1[9]) + (p1[10] + p1[11]);
                float t3 = (p1[12] + p1[13]) + (p1[14] + p1[15]);
                ps += (t0 + t1) + (t2 + t3);
            }
            lrun += cross_sum(ps);
            union { uint32_t u[4]; s16x8 v; } f00, f01, f10, f11;
            {
                uint32_t w0 = cvtpk_bf16(p0[0], p0[1]),   w1 = cvtpk_bf16(p0[2], p0[3]);
                uint32_t w2 = cvtpk_bf16(p0[4], p0[5]),   w3 = cvtpk_bf16(p0[6], p0[7]);
                uint32_t w4 = cvtpk_bf16(p0[8], p0[9]),   w5 = cvtpk_bf16(p0[10], p0[11]);
                uint32_t w6 = cvtpk_bf16(p0[12], p0[13]), w7 = cvtpk_bf16(p0[14], p0[15]);
                u32x2 r02 = pl32swap(w0, w2); f00.u[0] = r02[0]; f00.u[2] = r02[1];
                u32x2 r13 = pl32swap(w1, w3); f00.u[1] = r13[0]; f00.u[3] = r13[1];
                u32x2 r46 = pl32swap(w4, w6); f01.u[0] = r46[0]; f01.u[2] = r46[1];
                u32x2 r57 = pl32swap(w5, w7); f01.u[1] = r57[0]; f01.u[3] = r57[1];
            }
            if (have1) {
                uint32_t w0 = cvtpk_bf16(p1[0], p1[1]),   w1 = cvtpk_bf16(p1[2], p1[3]);
                uint32_t w2 = cvtpk_bf16(p1[4], p1[5]),   w3 = cvtpk_bf16(p1[6], p1[7]);
                uint32_t w4 = cvtpk_bf16(p1[8], p1[9]),   w5 = cvtpk_bf16(p1[10], p1[11]);
                uint32_t w6 = cvtpk_bf16(p1[12], p1[13]), w7 = cvtpk_bf16(p1[14], p1[15]);
                u32x2 r02 = pl32swap(w0, w2); f10.u[0] = r02[0]; f10.u[2] = r02[1];
                u32x2 r13 = pl32swap(w1, w3); f10.u[1] = r13[0]; f10.u[3] = r13[1];
                u32x2 r46 = pl32swap(w4, w6); f11.u[0] = r46[0]; f11.u[2] = r46[1];
                u32x2 r57 = pl32swap(w5, w7); f11.u[1] = r57[0]; f11.u[3] = r57[1];
            }
            __builtin_amdgcn_s_setprio(1);
#pragma unroll
            for (int dc = 0; dc < 4; ++dc) {
                const int dd = dc * 32 + ql;
                const int sw = (dd & 7);
                s16x8 v0 = *(const s16x8*)&Vs[dd * 64 + (((hi) ^ sw) << 3)];
                ov[dc] = mfma32(f00.v, v0, ov[dc]);
                s16x8 v1 = *(const s16x8*)&Vs[dd * 64 + (((2 + hi) ^ sw) << 3)];
                ov[dc] = mfma32(f01.v, v1, ov[dc]);
                if (have1) {
                    s16x8 v2 = *(const s16x8*)&Vs[dd * 64 + (((4 + hi) ^ sw) << 3)];
                    ov[dc] = mfma32(f10.v, v2, ov[dc]);
                    s16x8 v3 = *(const s16x8*)&Vs[dd * 64 + (((6 + hi) ^ sw) << 3)];
                    ov[dc] = mfma32(f11.v, v3, ov[dc]);
                }
            }
            __builtin_amdgcn_s_setprio(0);
        }
        asm volatile("s_waitcnt vmcnt(0)");
        __syncthreads();
        cur ^= 1;
    }

    float* mb = (float*)&KV[0][0][0];
    if (g == 1) {
#pragma unroll
        for (int dc = 0; dc < 4; ++dc)
#pragma unroll
            for (int r = 0; r < 16; ++r)
                mb[hw * 4096 + lane * 64 + dc * 16 + r] = ov[dc][r];
        mb[16384 + hw * 64 + lane] = mrun;
        mb[16640 + hw * 64 + lane] = lrun;
    }
    __syncthreads();
    if (g == 0) {
        const float m1 = mb[16384 + hw * 64 + lane];
        const float l1 = mb[16640 + hw * 64 + lane];
        const float mm = fmaxf(mrun, m1);
        const float al0 = __builtin_exp2f(mrun - mm);
        const float al1 = __builtin_exp2f(m1 - mm);
        lrun = lrun * al0 + l1 * al1;
#pragma unroll
        for (int r = 0; r < 16; ++r) {
            int cr = (r & 3) + 8 * (r >> 2) + 4 * hi;
            float a0r = __uint_as_float(
                (uint32_t)__builtin_amdgcn_ds_bpermute(cr << 2, (int)__float_as_uint(al0)));
            float a1r = __uint_as_float(
                (uint32_t)__builtin_amdgcn_ds_bpermute(cr << 2, (int)__float_as_uint(al1)));
#pragma unroll
            for (int dc = 0; dc < 4; ++dc)
                ov[dc][r] = ov[dc][r] * a0r + mb[hw * 4096 + lane * 64 + dc * 16 + r] * a1r;
        }
        WRITE_OUT(q0);
    }
#undef TILE_IDX
#undef STAGE_TILE
#undef WRITE_OUT
}

// ---------- launch ----------
extern "C" void kernel_launch(void* const* d_in, const int* in_sizes, int n_in,
                              void* d_out, int out_size, void* d_ws, size_t ws_size,
                              hipStream_t stream) {
    const float* x  = (const float*)d_in[0];
    const float* Wq = (const float*)d_in[1];
    const float* bq = (const float*)d_in[2];
    const float* Wk = (const float*)d_in[3];
    const float* bk = (const float*)d_in[4];
    const float* Wv = (const float*)d_in[5];
    const float* bv = (const float*)d_in[6];
    const float* Wo = (const float*)d_in[7];
    const float* bo = (const float*)d_in[8];
    const float* qn = (const float*)d_in[9];
    const float* kn = (const float*)d_in[10];
    const float* gl = (const float*)d_in[11];
    const int* sp   = (const int*)d_in[13];
    float* out = (float*)d_out;

    char* ws = (char*)d_ws;
    const size_t NEED = 96481280;
    if (ws_size < NEED) return;
    short* xb    = (short*)(ws + 0);            // 16 MiB, reused as Qb
    short* wqkvT = (short*)(ws + 16777216);     // 12 MiB
    short* woT   = (short*)(ws + 29360128);     // 8 MiB
    float* bqkv  = (float*)(ws + 37748736);     // 12 KiB
    short* Yb    = (short*)(ws + 37761024);     // 24 MiB bf16, head reused as attnb
    short* Kb    = (short*)(ws + 88092672);     // 4 MiB
    short* Vtb   = (short*)(ws + 92286976);     // 4 MiB
    short* Qb    = xb;
    short* attnb = Yb;

    f32_to_bf16_k<<<4096, 256, 0, stream>>>(x, xb, 1048576);
    transpose_f32_bf16_k<<<dim3(32, 32, 1), 256, 0, stream>>>(Wq, 0, 2048, wqkvT, 0, 2048);
    transpose_f32_bf16_k<<<dim3(8, 32, 1), 256, 0, stream>>>(Wk, 0, 512, wqkvT + (size_t)2048 * 2048, 0, 2048);
    transpose_f32_bf16_k<<<dim3(8, 32, 1), 256, 0, stream>>>(Wv, 0, 512, wqkvT + (size_t)2560 * 2048, 0, 2048);
    transpose_f32_bf16_k<<<dim3(32, 32, 1), 256, 0, stream>>>(Wo, 0, 2048, woT, 0, 2048);
    concat_bias_k<<<12, 256, 0, stream>>>(bq, bk, bv, bqkv);
    gemm256_k<0, true, 3><<<dim3(16, 16), 512, 0, stream>>>(xb, wqkvT, bqkv, Yb, 4096, 3072, 2048);
    qkv_post_k<<<4096, 256, 0, stream>>>(Yb, qn, kn, sp, Qb, Kb);
    transpose_bf16_k<<<dim3(8, 32, 2), 256, 0, stream>>>(
        Yb + 2560, (size_t)2048 * 3072, 3072, Vtb, (size_t)512 * 2048, 2048);
    attn_fwd_k<<<dim3(8, 32), 512, 0, stream>>>(Qb, Kb, Vtb, gl, attnb);
    gemm256_k<1, false, 2><<<dim3(16, 16), 512, 0, stream>>>(attnb, woT, bo, out, 4096, 2048, 2048);
}